// Round 1
// baseline (164600.684 us; speedup 1.0000x reference)
//
#include <hip/hip_runtime.h>

// ResLSTM: T=512 steps, B=128, IN=H=1024, L=4 layers.
// Round 1: correctness-first. One self-contained kernel per (t, layer):
//   - fused gates weight Wg[j] = [Wii | Wih | Wic] (bf16, K=3072) built per call in ws
//   - per-WG: compute i/f/o (K=3072) + cellgate (Whh, h-slice) + residual (Wir, out-slice)
//     in one unified K-walk, then LSTM elementwise in-register.
//   - state h,c kept in f32 (ping-pong by t parity); A-operands converted f32->bf16 in-register.

#define TT 512
#define BB 128
#define IN_D 1024
#define HH 1024
#define LL 4
#define G3 3072

typedef __attribute__((ext_vector_type(8))) __bf16 bf16x8;
typedef __attribute__((ext_vector_type(4))) __bf16 bf16x4;
typedef __attribute__((ext_vector_type(4))) float f32x4;

__device__ __forceinline__ f32x4 mfma16(bf16x8 a, bf16x8 b, f32x4 c) {
    return __builtin_amdgcn_mfma_f32_16x16x32_bf16(a, b, c, 0, 0, 0);
}

__device__ __forceinline__ bf16x8 ldb(const __bf16* p, int k) {
    return *reinterpret_cast<const bf16x8*>(p + k);  // 16B aligned: k % 8 == 0, rows 16B-aligned
}

__device__ __forceinline__ bf16x8 load_a(const float* p, int k) {
    float4 a0 = *reinterpret_cast<const float4*>(p + k);
    float4 a1 = *reinterpret_cast<const float4*>(p + k + 4);
    bf16x8 r;
    r[0] = (__bf16)a0.x; r[1] = (__bf16)a0.y; r[2] = (__bf16)a0.z; r[3] = (__bf16)a0.w;
    r[4] = (__bf16)a1.x; r[5] = (__bf16)a1.y; r[6] = (__bf16)a1.z; r[7] = (__bf16)a1.w;
    return r;
}

// ---- build fused gates weight: Wg[j][n][k], k<1024:Wii, k<2048:Wih, else:Wic ----
__global__ void k_conv_gates(const float* __restrict__ Wii,
                             const float* __restrict__ Wic,
                             const float* __restrict__ Wih,
                             __bf16* __restrict__ Wg) {
    const unsigned total = (unsigned)LL * G3 * G3;          // 37,748,736
    const unsigned stride = gridDim.x * blockDim.x * 4u;
    for (unsigned idx = (blockIdx.x * blockDim.x + threadIdx.x) * 4u; idx < total; idx += stride) {
        unsigned row = idx / G3;            // j*G3 + n
        int k = (int)(idx - row * G3);
        const float* src; int ks;
        if (k < 1024)      { src = Wii; ks = k; }
        else if (k < 2048) { src = Wih; ks = k - 1024; }
        else               { src = Wic; ks = k - 2048; }
        float4 v = *reinterpret_cast<const float4*>(src + (size_t)row * 1024 + ks);
        bf16x4 o;
        o[0] = (__bf16)v.x; o[1] = (__bf16)v.y; o[2] = (__bf16)v.z; o[3] = (__bf16)v.w;
        *reinterpret_cast<bf16x4*>(Wg + idx) = o;
    }
}

__global__ void k_conv_plain(const float* __restrict__ s, __bf16* __restrict__ d, unsigned total) {
    const unsigned stride = gridDim.x * blockDim.x * 4u;
    for (unsigned idx = (blockIdx.x * blockDim.x + threadIdx.x) * 4u; idx < total; idx += stride) {
        float4 v = *reinterpret_cast<const float4*>(s + idx);
        bf16x4 o;
        o[0] = (__bf16)v.x; o[1] = (__bf16)v.y; o[2] = (__bf16)v.z; o[3] = (__bf16)v.w;
        *reinterpret_cast<bf16x4*>(d + idx) = o;
    }
}

// hidden [2L,B,H] f32 -> hbuf parity0 (first L) / cbuf parity0 (last L)
__global__ void k_init(const float* __restrict__ hidden,
                       float* __restrict__ hbuf, float* __restrict__ cbuf) {
    const unsigned SLOT = LL * BB * HH;  // 524288
    const unsigned stride = gridDim.x * blockDim.x;
    for (unsigned i = blockIdx.x * blockDim.x + threadIdx.x; i < SLOT; i += stride) {
        hbuf[i] = hidden[i];
        cbuf[i] = hidden[SLOT + i];
    }
}

// final states (parity 0 after t=511) -> d_out tail: [hF | cF]
__global__ void k_final(const float* __restrict__ hbuf, const float* __restrict__ cbuf,
                        float* __restrict__ out_tail) {
    const unsigned SLOT = LL * BB * HH;
    const unsigned stride = gridDim.x * blockDim.x;
    for (unsigned i = blockIdx.x * blockDim.x + threadIdx.x; i < SLOT; i += stride) {
        out_tail[i] = hbuf[i];
        out_tail[SLOT + i] = cbuf[i];
    }
}

// one (t, layer) step. grid = (64, 2): n-tile (16 cols) x m-tile (64 rows); 4 waves of 16 rows.
__global__ __launch_bounds__(256) void k_step(
    const float* __restrict__ x,
    const __bf16* __restrict__ Wg,
    const __bf16* __restrict__ Whh,
    const __bf16* __restrict__ Wir,
    const float* __restrict__ bii,
    const float* __restrict__ bic,
    const float* __restrict__ bih,
    const float* __restrict__ bhh,
    float* __restrict__ hbuf,
    float* __restrict__ cbuf,
    float* __restrict__ dout,
    int t, int j)
{
    const int SLOT = LL * BB * HH;
    const int p = t & 1, pn = p ^ 1;
    const float* hsrc = hbuf + p * SLOT + j * BB * HH;
    const float* csrc = cbuf + p * SLOT + j * BB * HH;
    const float* osrc = (j == 0) ? (x + (size_t)t * BB * IN_D)
                                 : (hbuf + pn * SLOT + (j - 1) * BB * HH);
    float* hdst = hbuf + pn * SLOT + j * BB * HH;
    float* cdst = cbuf + pn * SLOT + j * BB * HH;

    const int lane = threadIdx.x & 63;
    const int wave = threadIdx.x >> 6;
    const int lrow = lane & 15;   // A row / B col / D col index within fragment
    const int kgrp = lane >> 4;   // k-group 0..3 (8 k each)
    const int n0 = blockIdx.x * 16;
    const int m0 = blockIdx.y * 64 + wave * 16;

    const __bf16* Wgj = Wg + (size_t)j * G3 * G3;
    const __bf16* wi = Wgj + (size_t)(n0 + lrow) * G3;            // i-gate rows
    const __bf16* wf = Wgj + (size_t)(1024 + n0 + lrow) * G3;     // f-gate rows
    const __bf16* wo = Wgj + (size_t)(2048 + n0 + lrow) * G3;     // o-gate rows
    const __bf16* wc = Whh + (size_t)j * HH * HH + (size_t)(n0 + lrow) * HH;
    const __bf16* wr = Wir + (size_t)j * HH * IN_D + (size_t)(n0 + lrow) * IN_D;

    const float* arow_o = osrc + (size_t)(m0 + lrow) * IN_D;
    const float* arow_h = hsrc + (size_t)(m0 + lrow) * HH;
    const float* arow_c = csrc + (size_t)(m0 + lrow) * HH;

    f32x4 ai = {0.f,0.f,0.f,0.f}, afv = {0.f,0.f,0.f,0.f}, ao = {0.f,0.f,0.f,0.f};
    f32x4 ac = {0.f,0.f,0.f,0.f}, ar  = {0.f,0.f,0.f,0.f};

    const int ko = kgrp * 8;

    // K-range 0: A = out (prev layer output / x), gates + residual (Wir)
    #pragma unroll 4
    for (int kt = 0; kt < 1024; kt += 32) {
        bf16x8 a = load_a(arow_o, kt + ko);
        ai  = mfma16(a, ldb(wi, kt + ko), ai);
        afv = mfma16(a, ldb(wf, kt + ko), afv);
        ao  = mfma16(a, ldb(wo, kt + ko), ao);
        ar  = mfma16(a, ldb(wr, kt + ko), ar);
    }
    // K-range 1: A = h, gates + cellgate (Whh)
    #pragma unroll 4
    for (int kt = 0; kt < 1024; kt += 32) {
        bf16x8 a = load_a(arow_h, kt + ko);
        ai  = mfma16(a, ldb(wi, 1024 + kt + ko), ai);
        afv = mfma16(a, ldb(wf, 1024 + kt + ko), afv);
        ao  = mfma16(a, ldb(wo, 1024 + kt + ko), ao);
        ac  = mfma16(a, ldb(wc, kt + ko), ac);
    }
    // K-range 2: A = c, gates only
    #pragma unroll 4
    for (int kt = 0; kt < 1024; kt += 32) {
        bf16x8 a = load_a(arow_c, kt + ko);
        ai  = mfma16(a, ldb(wi, 2048 + kt + ko), ai);
        afv = mfma16(a, ldb(wf, 2048 + kt + ko), afv);
        ao  = mfma16(a, ldb(wo, 2048 + kt + ko), ao);
    }

    const int col = n0 + lrow;
    const float b_i = bii[j*G3 + col]        + bih[j*G3 + col]        + bic[j*G3 + col];
    const float b_f = bii[j*G3 + HH + col]   + bih[j*G3 + HH + col]   + bic[j*G3 + HH + col];
    const float b_o = bii[j*G3 + 2*HH + col] + bih[j*G3 + 2*HH + col] + bic[j*G3 + 2*HH + col];
    const float b_c = bhh[j*HH + col];

    #pragma unroll
    for (int r = 0; r < 4; ++r) {
        const int m = m0 + kgrp * 4 + r;     // D row = (lane>>4)*4 + reg
        const size_t o = (size_t)m * HH + col;
        float iv = ai[r]  + b_i;
        float fv = afv[r] + b_f;
        float ov = ao[r]  + b_o;
        float cg = tanhf(ac[r] + b_c);
        float cold = csrc[o];
        float si = 1.f / (1.f + __expf(-iv));
        float sf = 1.f / (1.f + __expf(-fv));
        float so = 1.f / (1.f + __expf(-ov));
        float cy = sf * cold + si * cg;
        float hy = so * (tanhf(cy) + ar[r]);
        cdst[o] = cy;
        hdst[o] = hy;
        if (j == LL - 1) dout[(size_t)t * BB * HH + o] = hy;
    }
}

extern "C" void kernel_launch(void* const* d_in, const int* in_sizes, int n_in,
                              void* d_out, int out_size, void* d_ws, size_t ws_size,
                              hipStream_t stream) {
    const float* x      = (const float*)d_in[0];
    const float* hidden = (const float*)d_in[1];
    const float* Wii    = (const float*)d_in[2];
    const float* Wic    = (const float*)d_in[3];
    const float* Wih    = (const float*)d_in[4];
    const float* bii    = (const float*)d_in[5];
    const float* bic    = (const float*)d_in[6];
    const float* bih    = (const float*)d_in[7];
    const float* Whh    = (const float*)d_in[8];
    const float* bhh    = (const float*)d_in[9];
    const float* Wir    = (const float*)d_in[10];
    float* out = (float*)d_out;

    // workspace layout (bytes): Wg 75,497,472 | Whh_b 8,388,608 | Wir_b 8,388,608
    //                           hbuf 4,194,304 | cbuf 4,194,304   (total ~96 MiB)
    char* ws = (char*)d_ws;
    __bf16* Wg    = (__bf16*)(ws);
    __bf16* Whh_b = (__bf16*)(ws + 75497472);
    __bf16* Wir_b = (__bf16*)(ws + 83886080);
    float*  hbuf  = (float*)(ws + 92274688);
    float*  cbuf  = (float*)(ws + 96468992);

    k_conv_gates<<<4096, 256, 0, stream>>>(Wii, Wic, Wih, Wg);
    k_conv_plain<<<2048, 256, 0, stream>>>(Whh, Whh_b, (unsigned)(LL * HH * HH));
    k_conv_plain<<<2048, 256, 0, stream>>>(Wir, Wir_b, (unsigned)(LL * HH * IN_D));
    k_init<<<1024, 256, 0, stream>>>(hidden, hbuf, cbuf);

    dim3 grid(64, 2), block(256);
    for (int t = 0; t < TT; ++t)
        for (int j = 0; j < LL; ++j)
            k_step<<<grid, block, 0, stream>>>(x, Wg, Whh_b, Wir_b,
                                               bii, bic, bih, bhh,
                                               hbuf, cbuf, out, t, j);

    k_final<<<1024, 256, 0, stream>>>(hbuf, cbuf, out + (size_t)TT * BB * HH);
}

// Round 2
// 65027.295 us; speedup vs baseline: 2.5313x; 2.5313x over previous
//
#include <hip/hip_runtime.h>

// ResLSTM: T=512 steps, B=128, IN=H=1024, L=4 layers.
// Round 2: diagonal wavefront across layers (515 supersteps instead of 2048
// sequential (t,layer) launches), 8-wave WGs with BM=128 so each weight row is
// read by exactly one WG, precombined biases, fast exp-based activations.

#define TT 512
#define BB 128
#define IN_D 1024
#define HH 1024
#define LL 4
#define G3 3072
#define NSUPER (TT + LL - 1)

typedef __attribute__((ext_vector_type(8))) __bf16 bf16x8;
typedef __attribute__((ext_vector_type(4))) __bf16 bf16x4;
typedef __attribute__((ext_vector_type(4))) float f32x4;

__device__ __forceinline__ f32x4 mfma16(bf16x8 a, bf16x8 b, f32x4 c) {
    return __builtin_amdgcn_mfma_f32_16x16x32_bf16(a, b, c, 0, 0, 0);
}

__device__ __forceinline__ bf16x8 ldb(const __bf16* p, int k) {
    return *reinterpret_cast<const bf16x8*>(p + k);
}

__device__ __forceinline__ bf16x8 load_a(const float* p, int k) {
    float4 a0 = *reinterpret_cast<const float4*>(p + k);
    float4 a1 = *reinterpret_cast<const float4*>(p + k + 4);
    bf16x8 r;
    r[0] = (__bf16)a0.x; r[1] = (__bf16)a0.y; r[2] = (__bf16)a0.z; r[3] = (__bf16)a0.w;
    r[4] = (__bf16)a1.x; r[5] = (__bf16)a1.y; r[6] = (__bf16)a1.z; r[7] = (__bf16)a1.w;
    return r;
}

__device__ __forceinline__ float sigm(float v) { return 1.f / (1.f + __expf(-v)); }
__device__ __forceinline__ float tanh_fast(float v) { return 1.f - 2.f / (1.f + __expf(2.f * v)); }

// ---- build fused gates weight: Wg[j][n][k], k<1024:Wii, k<2048:Wih, else:Wic ----
__global__ void k_conv_gates(const float* __restrict__ Wii,
                             const float* __restrict__ Wic,
                             const float* __restrict__ Wih,
                             __bf16* __restrict__ Wg) {
    const unsigned total = (unsigned)LL * G3 * G3;
    const unsigned stride = gridDim.x * blockDim.x * 4u;
    for (unsigned idx = (blockIdx.x * blockDim.x + threadIdx.x) * 4u; idx < total; idx += stride) {
        unsigned row = idx / G3;            // j*G3 + n
        int k = (int)(idx - row * G3);
        const float* src; int ks;
        if (k < 1024)      { src = Wii; ks = k; }
        else if (k < 2048) { src = Wih; ks = k - 1024; }
        else               { src = Wic; ks = k - 2048; }
        float4 v = *reinterpret_cast<const float4*>(src + (size_t)row * 1024 + ks);
        bf16x4 o;
        o[0] = (__bf16)v.x; o[1] = (__bf16)v.y; o[2] = (__bf16)v.z; o[3] = (__bf16)v.w;
        *reinterpret_cast<bf16x4*>(Wg + idx) = o;
    }
}

__global__ void k_conv_plain(const float* __restrict__ s, __bf16* __restrict__ d, unsigned total) {
    const unsigned stride = gridDim.x * blockDim.x * 4u;
    for (unsigned idx = (blockIdx.x * blockDim.x + threadIdx.x) * 4u; idx < total; idx += stride) {
        float4 v = *reinterpret_cast<const float4*>(s + idx);
        bf16x4 o;
        o[0] = (__bf16)v.x; o[1] = (__bf16)v.y; o[2] = (__bf16)v.z; o[3] = (__bf16)v.w;
        *reinterpret_cast<bf16x4*>(d + idx) = o;
    }
}

// precombined biases: bsum[j][0..3071] = bii+bih+bic (gates), [3072..4095] = bhh
__global__ void k_bias(const float* __restrict__ bii, const float* __restrict__ bic,
                       const float* __restrict__ bih, const float* __restrict__ bhh,
                       float* __restrict__ bsum) {
    int i = blockIdx.x * blockDim.x + threadIdx.x;   // LL*4096 total
    int j = i >> 12, n = i & 4095;
    if (j >= LL) return;
    if (n < G3) bsum[j * 4096 + n] = bii[j * G3 + n] + bih[j * G3 + n] + bic[j * G3 + n];
    else        bsum[j * 4096 + n] = bhh[j * HH + (n - G3)];
}

// hidden [2L,B,H] -> parity-1 slots ("t = -1" state)
__global__ void k_init(const float* __restrict__ hidden,
                       float* __restrict__ hbuf, float* __restrict__ cbuf) {
    const unsigned SLOT = LL * BB * HH;
    const unsigned stride = gridDim.x * blockDim.x;
    for (unsigned i = blockIdx.x * blockDim.x + threadIdx.x; i < SLOT; i += stride) {
        hbuf[SLOT + i] = hidden[i];
        cbuf[SLOT + i] = hidden[SLOT + i];
    }
}

// final states: t=511 -> parity 1
__global__ void k_final(const float* __restrict__ hbuf, const float* __restrict__ cbuf,
                        float* __restrict__ out_tail) {
    const unsigned SLOT = LL * BB * HH;
    const unsigned stride = gridDim.x * blockDim.x;
    for (unsigned i = blockIdx.x * blockDim.x + threadIdx.x; i < SLOT; i += stride) {
        out_tail[i] = hbuf[SLOT + i];
        out_tail[SLOT + i] = cbuf[SLOT + i];
    }
}

// one superstep s: layer j (= blockIdx.y) processes t = s - j.
// grid (64, 4), block 512 (8 waves). Per WG: BM=128 (all batch) x BN=16 cols.
// wave w owns rows w*16..w*16+15; all waves share the same 16 weight cols (L1 reuse).
__global__ __launch_bounds__(512) void k_super(
    const float* __restrict__ x,
    const __bf16* __restrict__ Wg,
    const __bf16* __restrict__ Whh,
    const __bf16* __restrict__ Wir,
    const float* __restrict__ bsum,
    float* __restrict__ hbuf,
    float* __restrict__ cbuf,
    float* __restrict__ dout,
    int s)
{
    const int j = blockIdx.y;
    const int t = s - j;
    if (t < 0 || t >= TT) return;

    const int SLOT = BB * HH;
    const int p = t & 1, pp = p ^ 1;
    const float* hsrc = hbuf + (size_t)pp * LL * SLOT + (size_t)j * SLOT;
    const float* csrc = cbuf + (size_t)pp * LL * SLOT + (size_t)j * SLOT;
    const float* osrc = (j == 0) ? (x + (size_t)t * SLOT)
                                 : (hbuf + (size_t)p * LL * SLOT + (size_t)(j - 1) * SLOT);
    float* hdst = hbuf + (size_t)p * LL * SLOT + (size_t)j * SLOT;
    float* cdst = cbuf + (size_t)p * LL * SLOT + (size_t)j * SLOT;

    const int lane = threadIdx.x & 63;
    const int wave = threadIdx.x >> 6;
    const int lrow = lane & 15;   // A row / B col / D col within fragment
    const int kgrp = lane >> 4;   // k-group 0..3
    const int n0 = blockIdx.x * 16;
    const int m0 = wave * 16;

    const __bf16* Wgj = Wg + (size_t)j * G3 * G3;
    const __bf16* wi = Wgj + (size_t)(n0 + lrow) * G3;
    const __bf16* wf = Wgj + (size_t)(1024 + n0 + lrow) * G3;
    const __bf16* wo = Wgj + (size_t)(2048 + n0 + lrow) * G3;
    const __bf16* wc = Whh + (size_t)j * HH * HH + (size_t)(n0 + lrow) * HH;
    const __bf16* wr = Wir + (size_t)j * HH * IN_D + (size_t)(n0 + lrow) * IN_D;

    const float* arow_o = osrc + (size_t)(m0 + lrow) * IN_D;
    const float* arow_h = hsrc + (size_t)(m0 + lrow) * HH;
    const float* arow_c = csrc + (size_t)(m0 + lrow) * HH;

    f32x4 ai = {0.f,0.f,0.f,0.f}, afv = {0.f,0.f,0.f,0.f}, ao = {0.f,0.f,0.f,0.f};
    f32x4 ac = {0.f,0.f,0.f,0.f}, ar  = {0.f,0.f,0.f,0.f};

    const int ko = kgrp * 8;

    // K-range 0: A = layer input (prev layer h / x): gates + residual
    #pragma unroll 4
    for (int kt = 0; kt < 1024; kt += 32) {
        bf16x8 a = load_a(arow_o, kt + ko);
        ai  = mfma16(a, ldb(wi, kt + ko), ai);
        afv = mfma16(a, ldb(wf, kt + ko), afv);
        ao  = mfma16(a, ldb(wo, kt + ko), ao);
        ar  = mfma16(a, ldb(wr, kt + ko), ar);
    }
    // K-range 1: A = h: gates + cellgate
    #pragma unroll 4
    for (int kt = 0; kt < 1024; kt += 32) {
        bf16x8 a = load_a(arow_h, kt + ko);
        ai  = mfma16(a, ldb(wi, 1024 + kt + ko), ai);
        afv = mfma16(a, ldb(wf, 1024 + kt + ko), afv);
        ao  = mfma16(a, ldb(wo, 1024 + kt + ko), ao);
        ac  = mfma16(a, ldb(wc, kt + ko), ac);
    }
    // K-range 2: A = c: gates only
    #pragma unroll 4
    for (int kt = 0; kt < 1024; kt += 32) {
        bf16x8 a = load_a(arow_c, kt + ko);
        ai  = mfma16(a, ldb(wi, 2048 + kt + ko), ai);
        afv = mfma16(a, ldb(wf, 2048 + kt + ko), afv);
        ao  = mfma16(a, ldb(wo, 2048 + kt + ko), ao);
    }

    const int col = n0 + lrow;
    const float b_i = bsum[j * 4096 + col];
    const float b_f = bsum[j * 4096 + HH + col];
    const float b_o = bsum[j * 4096 + 2 * HH + col];
    const float b_c = bsum[j * 4096 + G3 + col];

    #pragma unroll
    for (int r = 0; r < 4; ++r) {
        const int m = m0 + kgrp * 4 + r;
        const size_t o = (size_t)m * HH + col;
        float iv = ai[r]  + b_i;
        float fv = afv[r] + b_f;
        float ov = ao[r]  + b_o;
        float cg = tanh_fast(ac[r] + b_c);
        float cold = csrc[o];
        float cy = sigm(fv) * cold + sigm(iv) * cg;
        float hy = sigm(ov) * (tanh_fast(cy) + ar[r]);
        cdst[o] = cy;
        hdst[o] = hy;
        if (j == LL - 1) dout[(size_t)t * BB * HH + o] = hy;
    }
}

extern "C" void kernel_launch(void* const* d_in, const int* in_sizes, int n_in,
                              void* d_out, int out_size, void* d_ws, size_t ws_size,
                              hipStream_t stream) {
    const float* x      = (const float*)d_in[0];
    const float* hidden = (const float*)d_in[1];
    const float* Wii    = (const float*)d_in[2];
    const float* Wic    = (const float*)d_in[3];
    const float* Wih    = (const float*)d_in[4];
    const float* bii    = (const float*)d_in[5];
    const float* bic    = (const float*)d_in[6];
    const float* bih    = (const float*)d_in[7];
    const float* Whh    = (const float*)d_in[8];
    const float* bhh    = (const float*)d_in[9];
    const float* Wir    = (const float*)d_in[10];
    float* out = (float*)d_out;

    // ws layout (bytes): Wg 75,497,472 | Whh_b 8,388,608 | Wir_b 8,388,608
    //                    hbuf 4,194,304 | cbuf 4,194,304 | bsum 65,536  (~100.7 MB)
    char* ws = (char*)d_ws;
    __bf16* Wg    = (__bf16*)(ws);
    __bf16* Whh_b = (__bf16*)(ws + 75497472);
    __bf16* Wir_b = (__bf16*)(ws + 83886080);
    float*  hbuf  = (float*)(ws + 92274688);
    float*  cbuf  = (float*)(ws + 96468992);
    float*  bsum  = (float*)(ws + 100663296);

    k_conv_gates<<<4096, 256, 0, stream>>>(Wii, Wic, Wih, Wg);
    k_conv_plain<<<2048, 256, 0, stream>>>(Whh, Whh_b, (unsigned)(LL * HH * HH));
    k_conv_plain<<<2048, 256, 0, stream>>>(Wir, Wir_b, (unsigned)(LL * HH * IN_D));
    k_bias<<<64, 256, 0, stream>>>(bii, bic, bih, bhh, bsum);
    k_init<<<1024, 256, 0, stream>>>(hidden, hbuf, cbuf);

    dim3 grid(64, 4), block(512);
    for (int s = 0; s < NSUPER; ++s)
        k_super<<<grid, block, 0, stream>>>(x, Wg, Whh_b, Wir_b, bsum, hbuf, cbuf, out, s);

    k_final<<<1024, 256, 0, stream>>>(hbuf, cbuf, out + (size_t)TT * BB * HH);
}

// Round 3
// 36084.988 us; speedup vs baseline: 4.5615x; 1.8021x over previous
//
#include <hip/hip_runtime.h>

// ResLSTM: T=512, B=128, IN=H=1024, L=4. Diagonal superstep wavefront (515 launches).
// R3: LDS-staged B via global_load_lds (XOR-swizzled source, linear LDS dest),
//     3-deep buffer rotation with counted vmcnt(3) + raw s_barrier (T3/T4),
//     bf16 state shadows for A-operands (f32 cell carry kept exact),
//     A-fragment register prefetch one chunk ahead.

#define TT 512
#define BB 128
#define IN_D 1024
#define HH 1024
#define LL 4
#define G3 3072
#define NSUPER (TT + LL - 1)
#define KC 64
#define NCHUNK 48
#define SB_TILE 2048
#define SB_BUF 8192
#define SLOT (BB * HH)
#define SLOT_ALL (LL * SLOT)

typedef __attribute__((ext_vector_type(8))) __bf16 bf16x8;
typedef __attribute__((ext_vector_type(4))) __bf16 bf16x4;
typedef __attribute__((ext_vector_type(4))) float f32x4;

typedef __attribute__((address_space(3))) void lds_void;
typedef const __attribute__((address_space(1))) void gmem_void;

__device__ __forceinline__ void gload_lds16(const void* g, void* l) {
    __builtin_amdgcn_global_load_lds((gmem_void*)g, (lds_void*)l, 16, 0, 0);
}

__device__ __forceinline__ f32x4 mfma16(bf16x8 a, bf16x8 b, f32x4 c) {
    return __builtin_amdgcn_mfma_f32_16x16x32_bf16(a, b, c, 0, 0, 0);
}

__device__ __forceinline__ bf16x8 ldb(const __bf16* p, int k) {
    return *reinterpret_cast<const bf16x8*>(p + k);
}

__device__ __forceinline__ bf16x8 load_a(const float* p, int k) {
    float4 a0 = *reinterpret_cast<const float4*>(p + k);
    float4 a1 = *reinterpret_cast<const float4*>(p + k + 4);
    bf16x8 r;
    r[0] = (__bf16)a0.x; r[1] = (__bf16)a0.y; r[2] = (__bf16)a0.z; r[3] = (__bf16)a0.w;
    r[4] = (__bf16)a1.x; r[5] = (__bf16)a1.y; r[6] = (__bf16)a1.z; r[7] = (__bf16)a1.w;
    return r;
}

__device__ __forceinline__ float sigm(float v) { return 1.f / (1.f + __expf(-v)); }
__device__ __forceinline__ float tanh_fast(float v) { return 1.f - 2.f / (1.f + __expf(2.f * v)); }

// ---- fused gates weight: Wg[j][n][k], k<1024:Wii, k<2048:Wih, else:Wic ----
__global__ void k_conv_gates(const float* __restrict__ Wii,
                             const float* __restrict__ Wic,
                             const float* __restrict__ Wih,
                             __bf16* __restrict__ Wg) {
    const unsigned total = (unsigned)LL * G3 * G3;
    const unsigned stride = gridDim.x * blockDim.x * 4u;
    for (unsigned idx = (blockIdx.x * blockDim.x + threadIdx.x) * 4u; idx < total; idx += stride) {
        unsigned row = idx / G3;
        int k = (int)(idx - row * G3);
        const float* src; int ks;
        if (k < 1024)      { src = Wii; ks = k; }
        else if (k < 2048) { src = Wih; ks = k - 1024; }
        else               { src = Wic; ks = k - 2048; }
        float4 v = *reinterpret_cast<const float4*>(src + (size_t)row * 1024 + ks);
        bf16x4 o;
        o[0] = (__bf16)v.x; o[1] = (__bf16)v.y; o[2] = (__bf16)v.z; o[3] = (__bf16)v.w;
        *reinterpret_cast<bf16x4*>(Wg + idx) = o;
    }
}

__global__ void k_conv_plain(const float* __restrict__ s, __bf16* __restrict__ d, unsigned total) {
    const unsigned stride = gridDim.x * blockDim.x * 4u;
    for (unsigned idx = (blockIdx.x * blockDim.x + threadIdx.x) * 4u; idx < total; idx += stride) {
        float4 v = *reinterpret_cast<const float4*>(s + idx);
        bf16x4 o;
        o[0] = (__bf16)v.x; o[1] = (__bf16)v.y; o[2] = (__bf16)v.z; o[3] = (__bf16)v.w;
        *reinterpret_cast<bf16x4*>(d + idx) = o;
    }
}

__global__ void k_bias(const float* __restrict__ bii, const float* __restrict__ bic,
                       const float* __restrict__ bih, const float* __restrict__ bhh,
                       float* __restrict__ bsum) {
    int i = blockIdx.x * blockDim.x + threadIdx.x;
    int j = i >> 12, n = i & 4095;
    if (j >= LL) return;
    if (n < G3) bsum[j * 4096 + n] = bii[j * G3 + n] + bih[j * G3 + n] + bic[j * G3 + n];
    else        bsum[j * 4096 + n] = bhh[j * HH + (n - G3)];
}

// hidden [2L,B,H] -> parity-1 slots ("t = -1")
__global__ void k_init(const float* __restrict__ hidden,
                       float* __restrict__ cbufF, __bf16* __restrict__ hb, __bf16* __restrict__ cb) {
    const unsigned stride = gridDim.x * blockDim.x;
    for (unsigned i = blockIdx.x * blockDim.x + threadIdx.x; i < SLOT_ALL; i += stride) {
        float hv = hidden[i];
        float cv = hidden[SLOT_ALL + i];
        hb[SLOT_ALL + i] = (__bf16)hv;
        cb[SLOT_ALL + i] = (__bf16)cv;
        cbufF[SLOT_ALL + i] = cv;
    }
}

// d_out tail: [hF | cF]; t=511 has parity 1
__global__ void k_final(const float* __restrict__ hfin, const float* __restrict__ cbufF,
                        float* __restrict__ out_tail) {
    const unsigned stride = gridDim.x * blockDim.x;
    for (unsigned i = blockIdx.x * blockDim.x + threadIdx.x; i < SLOT_ALL; i += stride) {
        out_tail[i] = hfin[i];
        out_tail[SLOT_ALL + i] = cbufF[SLOT_ALL + i];
    }
}

// superstep s: layer j = blockIdx.y processes t = s - j.
// grid (64,4), block 512 (8 waves). WG: BM=128 x BN=16. wave w rows w*16..+15.
// K walk: 48 chunks of KC=64: rg0 A=layer-in {wi,wf,wo,wr}; rg1 A=h {wi,wf,wo,wc}; rg2 A=c {wi,wf,wo}.
// B staged in LDS: tile = 16 rows x 64k bf16 = 16 x 128B, 16B slots XOR-swizzled by (row&7).
// Stage roles: wave w stages tile w>>1, half w&1 (one global_load_lds per chunk per wave).
__global__ __launch_bounds__(512) void k_super(
    const float* __restrict__ x,
    const __bf16* __restrict__ Wg,
    const __bf16* __restrict__ Whh,
    const __bf16* __restrict__ Wir,
    const float* __restrict__ bsum,
    float* __restrict__ cbufF,
    __bf16* __restrict__ hb,
    __bf16* __restrict__ cb,
    float* __restrict__ hfin,
    float* __restrict__ dout,
    int s)
{
    const int j = blockIdx.y;
    const int t = s - j;
    if (t < 0 || t >= TT) return;

    __shared__ __align__(16) char smem[3 * SB_BUF];   // 24 KiB

    const int p = t & 1, pp = p ^ 1;
    const float*  csrcF = cbufF + (size_t)pp * SLOT_ALL + (size_t)j * SLOT;
    float*        cdstF = cbufF + (size_t)p  * SLOT_ALL + (size_t)j * SLOT;
    const __bf16* hsrcB = hb + (size_t)pp * SLOT_ALL + (size_t)j * SLOT;
    const __bf16* csrcB = cb + (size_t)pp * SLOT_ALL + (size_t)j * SLOT;
    const __bf16* osrcB = hb + (size_t)p * SLOT_ALL + (size_t)(j - 1) * SLOT;  // j>0
    const float*  osrcF = x + (size_t)t * SLOT;                                // j==0
    __bf16* hdstB = hb + (size_t)p * SLOT_ALL + (size_t)j * SLOT;
    __bf16* cdstB = cb + (size_t)p * SLOT_ALL + (size_t)j * SLOT;

    const int tid  = threadIdx.x;
    const int lane = tid & 63;
    const int wave = tid >> 6;
    const int lrow = lane & 15;
    const int kgrp = lane >> 4;
    const int n0 = blockIdx.x * 16;
    const int m0 = wave * 16;

    // ---- staging role (per wave: one tile-half) ----
    const int st_tile = wave >> 1;
    const int st_half = wave & 1;
    const int st_r = st_half * 8 + (lane >> 3);   // weight row within tile (0..15)
    const int st_s = lane & 7;                    // physical 16B slot
    const int st_k8 = ((st_s ^ (st_r & 7)) << 3); // logical k element offset (XOR swizzle)
    const __bf16* Wgj = Wg + (size_t)j * G3 * G3;
    const __bf16* st_g  = Wgj + (size_t)(st_tile * 1024 + n0 + st_r) * G3 + st_k8;  // tiles 0..2 (k contiguous over 3072)
    const __bf16* st_wr = Wir + (size_t)j * HH * IN_D + (size_t)(n0 + st_r) * IN_D + st_k8;
    const __bf16* st_wc = Whh + (size_t)j * HH * HH + (size_t)(n0 + st_r) * HH + st_k8;
    char* st_dst = smem + st_tile * SB_TILE + st_half * 1024;

    auto stage = [&](int c) {
        if (c >= NCHUNK) return;
        char* dst = st_dst + (c % 3) * SB_BUF;
        if (st_tile < 3) {
            gload_lds16(st_g + (size_t)c * KC, dst);
        } else {
            const int r = c >> 4, kb = (c & 15) << 6;
            if (r == 0)      gload_lds16(st_wr + kb, dst);
            else if (r == 1) gload_lds16(st_wc + kb, dst);
            // r==2: no tile 3
        }
    };

    // ---- compute-side lane constants ----
    const int dsrow = lrow << 7;                  // row * 128B
    const int x7 = lrow & 7;
    const int so0 = ((kgrp ^ x7) << 4);           // ksub 0 slot byte offset
    const int so1 = (((4 | kgrp) ^ x7) << 4);     // ksub 1

    const int aoff = (m0 + lrow) * HH + (kgrp << 3);
    const __bf16* aH = hsrcB + aoff;
    const __bf16* aC = csrcB + aoff;
    const __bf16* aO = osrcB + aoff;
    const float*  aX = osrcF + aoff;

    auto loadA = [&](int c, bf16x8& r0, bf16x8& r1) {
        const int rg = c >> 4, kt = (c & 15) << 6;
        if (rg == 0) {
            if (j == 0) { r0 = load_a(aX, kt); r1 = load_a(aX, kt + 32); }
            else        { r0 = ldb(aO, kt);    r1 = ldb(aO, kt + 32); }
        } else if (rg == 1) { r0 = ldb(aH, kt); r1 = ldb(aH, kt + 32); }
        else                { r0 = ldb(aC, kt); r1 = ldb(aC, kt + 32); }
    };

    f32x4 vi = {0,0,0,0}, vf = {0,0,0,0}, vo = {0,0,0,0}, vc = {0,0,0,0}, vr = {0,0,0,0};

    bf16x8 a0, a1, na0, na1;
    stage(0); stage(1);
    loadA(0, a0, a1);
    asm volatile("s_waitcnt vmcnt(3)" ::: "memory");
    __builtin_amdgcn_s_barrier();

    for (int c = 0; c < NCHUNK; ++c) {
        const int rg = c >> 4;
        char* bs = smem + (c % 3) * SB_BUF;

        if (c + 1 < NCHUNK) loadA(c + 1, na0, na1);
        stage(c + 2);

        bf16x8 b;
        b = *(const bf16x8*)(bs + 0 * SB_TILE + dsrow + so0); vi = mfma16(a0, b, vi);
        b = *(const bf16x8*)(bs + 1 * SB_TILE + dsrow + so0); vf = mfma16(a0, b, vf);
        b = *(const bf16x8*)(bs + 2 * SB_TILE + dsrow + so0); vo = mfma16(a0, b, vo);
        if (rg == 0)      { b = *(const bf16x8*)(bs + 3 * SB_TILE + dsrow + so0); vr = mfma16(a0, b, vr); }
        else if (rg == 1) { b = *(const bf16x8*)(bs + 3 * SB_TILE + dsrow + so0); vc = mfma16(a0, b, vc); }
        b = *(const bf16x8*)(bs + 0 * SB_TILE + dsrow + so1); vi = mfma16(a1, b, vi);
        b = *(const bf16x8*)(bs + 1 * SB_TILE + dsrow + so1); vf = mfma16(a1, b, vf);
        b = *(const bf16x8*)(bs + 2 * SB_TILE + dsrow + so1); vo = mfma16(a1, b, vo);
        if (rg == 0)      { b = *(const bf16x8*)(bs + 3 * SB_TILE + dsrow + so1); vr = mfma16(a1, b, vr); }
        else if (rg == 1) { b = *(const bf16x8*)(bs + 3 * SB_TILE + dsrow + so1); vc = mfma16(a1, b, vc); }

        a0 = na0; a1 = na1;
        // leave {A(c+1) x2, stage(c+2)} in flight; guarantees stage(c+1) retired (in-order vmcnt)
        asm volatile("s_waitcnt vmcnt(3)" ::: "memory");
        __builtin_amdgcn_s_barrier();
    }

    // ---- elementwise epilogue ----
    const int col = n0 + lrow;
    const float b_i = bsum[j * 4096 + col];
    const float b_f = bsum[j * 4096 + HH + col];
    const float b_o = bsum[j * 4096 + 2 * HH + col];
    const float b_c = bsum[j * 4096 + G3 + col];

    #pragma unroll
    for (int r = 0; r < 4; ++r) {
        const int m = m0 + kgrp * 4 + r;
        const size_t o = (size_t)m * HH + col;
        float iv = vi[r] + b_i;
        float fv = vf[r] + b_f;
        float ov = vo[r] + b_o;
        float cg = tanh_fast(vc[r] + b_c);
        float cold = csrcF[o];
        float cy = sigm(fv) * cold + sigm(iv) * cg;
        float hy = sigm(ov) * (tanh_fast(cy) + vr[r]);
        cdstF[o] = cy;
        cdstB[o] = (__bf16)cy;
        hdstB[o] = (__bf16)hy;
        if (t == TT - 1) hfin[(size_t)j * SLOT + o] = hy;
        if (j == LL - 1) dout[(size_t)t * SLOT + o] = hy;
    }
}

extern "C" void kernel_launch(void* const* d_in, const int* in_sizes, int n_in,
                              void* d_out, int out_size, void* d_ws, size_t ws_size,
                              hipStream_t stream) {
    const float* x      = (const float*)d_in[0];
    const float* hidden = (const float*)d_in[1];
    const float* Wii    = (const float*)d_in[2];
    const float* Wic    = (const float*)d_in[3];
    const float* Wih    = (const float*)d_in[4];
    const float* bii    = (const float*)d_in[5];
    const float* bic    = (const float*)d_in[6];
    const float* bih    = (const float*)d_in[7];
    const float* Whh    = (const float*)d_in[8];
    const float* bhh    = (const float*)d_in[9];
    const float* Wir    = (const float*)d_in[10];
    float* out = (float*)d_out;

    // ws layout (bytes):
    //   Wg     @ 0          75,497,472
    //   Whh_b  @ 75497472    8,388,608
    //   Wir_b  @ 83886080    8,388,608
    //   cbufF  @ 92274688    4,194,304   (2 parities x L x B x H f32)
    //   bsum   @ 96468992       65,536
    //   hb     @ 96534528    2,097,152   (2 parities, bf16)
    //   cb     @ 98631680    2,097,152
    //   hfin   @ 100728832   2,097,152
    char* ws = (char*)d_ws;
    __bf16* Wg    = (__bf16*)(ws);
    __bf16* Whh_b = (__bf16*)(ws + 75497472);
    __bf16* Wir_b = (__bf16*)(ws + 83886080);
    float*  cbufF = (float*)(ws + 92274688);
    float*  bsum  = (float*)(ws + 96468992);
    __bf16* hb    = (__bf16*)(ws + 96534528);
    __bf16* cb    = (__bf16*)(ws + 98631680);
    float*  hfin  = (float*)(ws + 100728832);

    k_conv_gates<<<4096, 256, 0, stream>>>(Wii, Wic, Wih, Wg);
    k_conv_plain<<<2048, 256, 0, stream>>>(Whh, Whh_b, (unsigned)(LL * HH * HH));
    k_conv_plain<<<2048, 256, 0, stream>>>(Wir, Wir_b, (unsigned)(LL * HH * IN_D));
    k_bias<<<64, 256, 0, stream>>>(bii, bic, bih, bhh, bsum);
    k_init<<<1024, 256, 0, stream>>>(hidden, cbufF, hb, cb);

    dim3 grid(64, 4), block(512);
    for (int s = 0; s < NSUPER; ++s)
        k_super<<<grid, block, 0, stream>>>(x, Wg, Whh_b, Wir_b, bsum,
                                            cbufF, hb, cb, hfin, out, s);

    k_final<<<1024, 256, 0, stream>>>(hfin, cbufF, out + (size_t)TT * SLOT);
}